// Round 1
// baseline (97.497 us; speedup 1.0000x reference)
//
#include <hip/hip_runtime.h>

// Soft-sphere multi-species: energy + analytic forces.
// N=4096 particles, S=8 species. O(N^2) tiled pair kernel.
// Grid: (N/TI) i-tiles x (N/TJ) j-chunks. Each thread owns one particle i,
// iterates a j-chunk staged in LDS. Forces merged across j-chunks by atomicAdd.

#define TI 256
#define TJ 128
#define CUT2 2.25f  // CUTOFF=1.5 squared

__global__ __launch_bounds__(TI) void soft_sphere_kernel(
    const float* __restrict__ pos,
    const float* __restrict__ cell,
    const float* __restrict__ sigm,
    const float* __restrict__ epsm,
    const float* __restrict__ alpm,
    const int*   __restrict__ spec,
    float* __restrict__ out,   // out[0]=energy, out[1..3N]=forces
    int n)
{
    __shared__ float sh_px[TJ], sh_py[TJ], sh_pz[TJ];
    __shared__ int   sh_sp[TJ];
    __shared__ float sh_sig[64], sh_eps[64], sh_alp[64];
    __shared__ float sh_e[TI / 64];

    const int tid = threadIdx.x;

    // Stage species-pair matrices (8x8 each) into LDS.
    if (tid < 64) {
        sh_sig[tid] = sigm[tid];
        sh_eps[tid] = epsm[tid];
        sh_alp[tid] = alpm[tid];
    }

    // Stage this block's j-chunk of positions+species into LDS.
    const int j0 = blockIdx.y * TJ;
    for (int t = tid; t < TJ; t += TI) {
        int j = j0 + t;
        sh_px[t] = pos[3 * j + 0];
        sh_py[t] = pos[3 * j + 1];
        sh_pz[t] = pos[3 * j + 2];
        sh_sp[t] = spec[j];
    }

    // Cell and its inverse (uniform -> SGPRs; ~40 flops once per thread).
    const float m00 = cell[0], m01 = cell[1], m02 = cell[2];
    const float m10 = cell[3], m11 = cell[4], m12 = cell[5];
    const float m20 = cell[6], m21 = cell[7], m22 = cell[8];
    const float det = m00 * (m11 * m22 - m12 * m21)
                    - m01 * (m10 * m22 - m12 * m20)
                    + m02 * (m10 * m21 - m11 * m20);
    const float rdet = 1.0f / det;
    const float i00 = (m11 * m22 - m12 * m21) * rdet;
    const float i01 = (m02 * m21 - m01 * m22) * rdet;
    const float i02 = (m01 * m12 - m02 * m11) * rdet;
    const float i10 = (m12 * m20 - m10 * m22) * rdet;
    const float i11 = (m00 * m22 - m02 * m20) * rdet;
    const float i12 = (m02 * m10 - m00 * m12) * rdet;
    const float i20 = (m10 * m21 - m11 * m20) * rdet;
    const float i21 = (m01 * m20 - m00 * m21) * rdet;
    const float i22 = (m00 * m11 - m01 * m10) * rdet;

    const int i = blockIdx.x * TI + tid;
    const float px = pos[3 * i + 0];
    const float py = pos[3 * i + 1];
    const float pz = pos[3 * i + 2];
    const int   si8 = spec[i] << 3;

    __syncthreads();

    float e_acc = 0.0f, fxa = 0.0f, fya = 0.0f, fza = 0.0f;

#pragma unroll 4
    for (int t = 0; t < TJ; ++t) {
        float dx = sh_px[t] - px;
        float dy = sh_py[t] - py;
        float dz = sh_pz[t] - pz;
        // frac = dr @ inv_cell (row vector)
        float fx = dx * i00 + dy * i10 + dz * i20;
        float fy = dx * i01 + dy * i11 + dz * i21;
        float fz = dx * i02 + dy * i12 + dz * i22;
        // minimum image: frac -= round(frac)  (rintf = round-half-even, matches jnp.round)
        fx -= rintf(fx);
        fy -= rintf(fy);
        fz -= rintf(fz);
        // dr = frac @ cell
        float ddx = fx * m00 + fy * m10 + fz * m20;
        float ddy = fx * m01 + fy * m11 + fz * m21;
        float ddz = fx * m02 + fy * m12 + fz * m22;
        float r2 = ddx * ddx + ddy * ddy + ddz * ddz;

        if (r2 < CUT2 && (j0 + t) != i) {
            float r  = sqrtf(r2);
            int  idx = si8 + sh_sp[t];
            float sg = sh_sig[idx];
            float f  = 1.0f - r / sg;
            if (f > 0.0f) {
                float ep  = sh_eps[idx];
                float al  = sh_alp[idx];
                float fa1 = powf(f, al - 1.0f);      // f^(alpha-1)
                e_acc += ep / al * fa1 * f;          // (eps/alpha) f^alpha
                // F_i += (de/dr) * dr_vec / r, de/dr = -(eps/sigma) f^(alpha-1)
                float c = ep * fa1 / (sg * r);
                fxa -= c * ddx;
                fya -= c * ddy;
                fza -= c * ddz;
            }
        }
    }

    // Merge partial forces across j-chunk blocks.
    atomicAdd(&out[1 + 3 * i + 0], fxa);
    atomicAdd(&out[1 + 3 * i + 1], fya);
    atomicAdd(&out[1 + 3 * i + 2], fza);

    // Energy: wave shuffle reduce -> LDS across 4 waves -> one atomic per block.
    for (int off = 32; off > 0; off >>= 1)
        e_acc += __shfl_down(e_acc, off, 64);
    if ((tid & 63) == 0) sh_e[tid >> 6] = e_acc;
    __syncthreads();
    if (tid == 0) {
        float tot = 0.0f;
        for (int w = 0; w < TI / 64; ++w) tot += sh_e[w];
        atomicAdd(&out[0], 0.5f * tot);  // ordered pairs counted twice
    }
}

extern "C" void kernel_launch(void* const* d_in, const int* in_sizes, int n_in,
                              void* d_out, int out_size, void* d_ws, size_t ws_size,
                              hipStream_t stream) {
    const float* pos  = (const float*)d_in[0];
    const float* cell = (const float*)d_in[1];
    const float* sigm = (const float*)d_in[2];
    const float* epsm = (const float*)d_in[3];
    const float* alpm = (const float*)d_in[4];
    const int*   spec = (const int*)d_in[5];
    float* out = (float*)d_out;
    const int n = in_sizes[5];  // species count = N

    // Harness poisons d_out with 0xAA before every timed launch; we accumulate
    // with atomics, so zero it first (async memset is graph-capture safe).
    hipMemsetAsync(out, 0, (size_t)out_size * sizeof(float), stream);

    dim3 grid(n / TI, (n + TJ - 1) / TJ);
    soft_sphere_kernel<<<grid, TI, 0, stream>>>(pos, cell, sigm, epsm, alpm,
                                                spec, out, n);
}

// Round 3
// 92.721 us; speedup vs baseline: 1.0515x; 1.0515x over previous
//
#include <hip/hip_runtime.h>

// Soft-sphere multi-species: energy + analytic forces. N=4096, S=8.
// O(N^2) tiled pair kernel. Grid: (N/TI) i-tiles x (N/TJ) j-chunks.
// Each thread owns particle i; j-chunk staged in LDS as float4 (xyz+species).
// Diagonal-cell fast path (uniform branch): per-axis minimum image.
// Per-pair tables {1/sig, alpha-1, eps/alpha, eps/sig} precomputed in LDS.
// f^(alpha-1) via hardware v_exp_f32/v_log_f32 (__builtin_amdgcn_*): f in (0,1],
// rel err ~2^-21 * alpha — absmax stays ~1e-3, threshold is 5.28.

#define TI 256
#define TJ 64
#define CUT2 2.25f  // CUTOFF=1.5 squared

__device__ __forceinline__ float fast_pow(float f, float e) {
    // f > 0 guaranteed. 2^(e * log2(f)) on the hardware transcendental pipe.
    return __builtin_amdgcn_exp2f(e * __builtin_amdgcn_logf(f));
}

__global__ __launch_bounds__(TI) void soft_sphere_kernel(
    const float* __restrict__ pos,
    const float* __restrict__ cell,
    const float* __restrict__ sigm,
    const float* __restrict__ epsm,
    const float* __restrict__ alpm,
    const int*   __restrict__ spec,
    float* __restrict__ out,   // out[0]=energy, out[1..3N]=forces
    int n)
{
    __shared__ float4 sh_pos[TJ];   // j positions + species bits in .w
    __shared__ float4 sh_tab[64];   // {inv_sig, alpha-1, eps/alpha, eps/sig}
    __shared__ float  sh_e[TI / 64];

    const int tid = threadIdx.x;
    const int j0  = blockIdx.y * TJ;

    if (tid < 64) {
        // Species-pair coefficient tables (8x8 = 64 entries).
        float sg = sigm[tid], ep = epsm[tid], al = alpm[tid];
        float inv_sg = 1.0f / sg;
        sh_tab[tid] = make_float4(inv_sg, al - 1.0f, ep / al, ep * inv_sg);
        // j-chunk staging (TJ == 64).
        int j = j0 + tid;
        sh_pos[tid] = make_float4(pos[3 * j + 0], pos[3 * j + 1],
                                  pos[3 * j + 2], __int_as_float(spec[j]));
    }

    // Cell (uniform -> SGPRs).
    const float m00 = cell[0], m01 = cell[1], m02 = cell[2];
    const float m10 = cell[3], m11 = cell[4], m12 = cell[5];
    const float m20 = cell[6], m21 = cell[7], m22 = cell[8];
    const bool diag = (m01 == 0.0f) & (m02 == 0.0f) & (m10 == 0.0f) &
                      (m12 == 0.0f) & (m20 == 0.0f) & (m21 == 0.0f);

    const int   i   = blockIdx.x * TI + tid;
    const float px  = pos[3 * i + 0];
    const float py  = pos[3 * i + 1];
    const float pz  = pos[3 * i + 2];
    const int   si8 = spec[i] << 3;

    __syncthreads();

    float e_acc = 0.0f, fxa = 0.0f, fya = 0.0f, fza = 0.0f;

    if (diag) {
        // Orthorhombic fast path: per-axis minimum image.
        const float iLx = 1.0f / m00, iLy = 1.0f / m11, iLz = 1.0f / m22;
#pragma unroll 4
        for (int t = 0; t < TJ; ++t) {
            float4 pj = sh_pos[t];
            float dx = pj.x - px;
            float dy = pj.y - py;
            float dz = pj.z - pz;
            dx = fmaf(-rintf(dx * iLx), m00, dx);
            dy = fmaf(-rintf(dy * iLy), m11, dy);
            dz = fmaf(-rintf(dz * iLz), m22, dz);
            float r2 = fmaf(dx, dx, fmaf(dy, dy, dz * dz));
            if (r2 < CUT2 && (j0 + t) != i) {
                float4 tab = sh_tab[si8 + __float_as_int(pj.w)];
                float rinv = rsqrtf(r2);
                float r    = r2 * rinv;
                float f    = fmaf(-r, tab.x, 1.0f);   // 1 - r/sig
                if (f > 0.0f) {
                    float p = fast_pow(f, tab.y);        // f^(alpha-1)
                    e_acc = fmaf(tab.z * p, f, e_acc);   // eps/alpha * f^alpha
                    float c = tab.w * p * rinv;          // eps/(sig*r) * f^(a-1)
                    fxa = fmaf(-c, dx, fxa);
                    fya = fmaf(-c, dy, fya);
                    fza = fmaf(-c, dz, fza);
                }
            }
        }
    } else {
        // General triclinic path (never taken for this input, kept for correctness).
        const float det = m00 * (m11 * m22 - m12 * m21)
                        - m01 * (m10 * m22 - m12 * m20)
                        + m02 * (m10 * m21 - m11 * m20);
        const float rdet = 1.0f / det;
        const float i00 = (m11 * m22 - m12 * m21) * rdet;
        const float i01 = (m02 * m21 - m01 * m22) * rdet;
        const float i02 = (m01 * m12 - m02 * m11) * rdet;
        const float i10 = (m12 * m20 - m10 * m22) * rdet;
        const float i11 = (m00 * m22 - m02 * m20) * rdet;
        const float i12 = (m02 * m10 - m00 * m12) * rdet;
        const float i20 = (m10 * m21 - m11 * m20) * rdet;
        const float i21 = (m01 * m20 - m00 * m21) * rdet;
        const float i22 = (m00 * m11 - m01 * m10) * rdet;
#pragma unroll 2
        for (int t = 0; t < TJ; ++t) {
            float4 pj = sh_pos[t];
            float dx = pj.x - px, dy = pj.y - py, dz = pj.z - pz;
            float fx = dx * i00 + dy * i10 + dz * i20;
            float fy = dx * i01 + dy * i11 + dz * i21;
            float fz = dx * i02 + dy * i12 + dz * i22;
            fx -= rintf(fx); fy -= rintf(fy); fz -= rintf(fz);
            float ddx = fx * m00 + fy * m10 + fz * m20;
            float ddy = fx * m01 + fy * m11 + fz * m21;
            float ddz = fx * m02 + fy * m12 + fz * m22;
            float r2 = fmaf(ddx, ddx, fmaf(ddy, ddy, ddz * ddz));
            if (r2 < CUT2 && (j0 + t) != i) {
                float4 tab = sh_tab[si8 + __float_as_int(pj.w)];
                float rinv = rsqrtf(r2);
                float r    = r2 * rinv;
                float f    = fmaf(-r, tab.x, 1.0f);
                if (f > 0.0f) {
                    float p = fast_pow(f, tab.y);
                    e_acc = fmaf(tab.z * p, f, e_acc);
                    float c = tab.w * p * rinv;
                    fxa = fmaf(-c, ddx, fxa);
                    fya = fmaf(-c, ddy, fya);
                    fza = fmaf(-c, ddz, fza);
                }
            }
        }
    }

    // Merge partial forces across j-chunk blocks.
    atomicAdd(&out[1 + 3 * i + 0], fxa);
    atomicAdd(&out[1 + 3 * i + 1], fya);
    atomicAdd(&out[1 + 3 * i + 2], fza);

    // Energy: wave shuffle reduce -> LDS across waves -> one atomic per block.
    for (int off = 32; off > 0; off >>= 1)
        e_acc += __shfl_down(e_acc, off, 64);
    if ((tid & 63) == 0) sh_e[tid >> 6] = e_acc;
    __syncthreads();
    if (tid == 0) {
        float tot = 0.0f;
        for (int w = 0; w < TI / 64; ++w) tot += sh_e[w];
        atomicAdd(&out[0], 0.5f * tot);  // ordered pairs counted twice
    }
}

extern "C" void kernel_launch(void* const* d_in, const int* in_sizes, int n_in,
                              void* d_out, int out_size, void* d_ws, size_t ws_size,
                              hipStream_t stream) {
    const float* pos  = (const float*)d_in[0];
    const float* cell = (const float*)d_in[1];
    const float* sigm = (const float*)d_in[2];
    const float* epsm = (const float*)d_in[3];
    const float* alpm = (const float*)d_in[4];
    const int*   spec = (const int*)d_in[5];
    float* out = (float*)d_out;
    const int n = in_sizes[5];  // species array length = N

    // We accumulate with atomics; harness poisons d_out with 0xAA each launch.
    (void)hipMemsetAsync(out, 0, (size_t)out_size * sizeof(float), stream);

    dim3 grid(n / TI, (n + TJ - 1) / TJ);
    soft_sphere_kernel<<<grid, TI, 0, stream>>>(pos, cell, sigm, epsm, alpm,
                                                spec, out, n);
}